// Round 11
// baseline (343.454 us; speedup 1.0000x reference)
//
#include <hip/hip_runtime.h>
#include <hip/hip_bf16.h>

#define NN 16384
#define NE 524288
#define FIN 256
#define HH1 64
#define HH2 32

typedef __attribute__((ext_vector_type(8))) short bf16x8;
typedef __attribute__((ext_vector_type(4))) float f32x4;

// ---------------- H0 = x @ W1; trailing blocks zero cnt ----------------
__global__ __launch_bounds__(256) void gemm_xw1_zero(const float* __restrict__ x,
                                                     const float* __restrict__ W1,
                                                     float* __restrict__ H0,
                                                     int* __restrict__ cnt) {
  if (blockIdx.x >= 256) {                       // 64 trailing blocks: zero cnt[16384]
    int i = (blockIdx.x - 256) * 256 + threadIdx.x;
    cnt[i] = 0;
    return;
  }
  __shared__ float xs[64][65];
  __shared__ float ws[64][65];
  const int t = threadIdx.x;
  const int row0 = blockIdx.x * 64;
  const int tr = t >> 4, tc = t & 15;
  float acc[4][4] = {};
  for (int kc = 0; kc < FIN; kc += 64) {
#pragma unroll
    for (int i = 0; i < 4; ++i) {
      int slot = t + i * 256;
      int r = slot >> 4, c4 = (slot & 15) * 4;
      float4 v = *reinterpret_cast<const float4*>(&x[(size_t)(row0 + r) * FIN + kc + c4]);
      xs[r][c4 + 0] = v.x; xs[r][c4 + 1] = v.y; xs[r][c4 + 2] = v.z; xs[r][c4 + 3] = v.w;
      float4 wv = *reinterpret_cast<const float4*>(&W1[(size_t)(kc + r) * HH1 + c4]);
      ws[r][c4 + 0] = wv.x; ws[r][c4 + 1] = wv.y; ws[r][c4 + 2] = wv.z; ws[r][c4 + 3] = wv.w;
    }
    __syncthreads();
#pragma unroll
    for (int k = 0; k < 64; ++k) {
      float a[4], b[4];
#pragma unroll
      for (int i = 0; i < 4; ++i) a[i] = xs[tr * 4 + i][k];
#pragma unroll
      for (int j = 0; j < 4; ++j) b[j] = ws[k][tc * 4 + j];
#pragma unroll
      for (int i = 0; i < 4; ++i)
#pragma unroll
        for (int j = 0; j < 4; ++j) acc[i][j] += a[i] * b[j];
    }
    __syncthreads();
  }
#pragma unroll
  for (int i = 0; i < 4; ++i) {
    float4 o; o.x = acc[i][0]; o.y = acc[i][1]; o.z = acc[i][2]; o.w = acc[i][3];
    *reinterpret_cast<float4*>(&H0[(size_t)(row0 + tr * 4 + i) * HH1 + tc * 4]) = o;
  }
}

// ---------------- counting sort of edges by src ----------------
__global__ __launch_bounds__(256) void hist_src(const int* __restrict__ src,
                                                int* __restrict__ cnt) {
  int e = blockIdx.x * 256 + threadIdx.x;
  if (e < NE) atomicAdd(&cnt[src[e]], 1);
}

// single block, 256 threads: vector loads + shuffle scan
__global__ __launch_bounds__(256) void scan_offsets(const int* __restrict__ cnt,
                                                    int* __restrict__ off,
                                                    int* __restrict__ cur) {
  __shared__ int wsum[4];
  __shared__ int wpre[4];
  const int t = threadIdx.x;
  const int lane = t & 63, w = t >> 6;
  int v[64];
#pragma unroll
  for (int i = 0; i < 16; ++i) {
    int4 q = reinterpret_cast<const int4*>(cnt)[t * 16 + i];
    v[i * 4 + 0] = q.x; v[i * 4 + 1] = q.y; v[i * 4 + 2] = q.z; v[i * 4 + 3] = q.w;
  }
  int s = 0;
#pragma unroll
  for (int i = 0; i < 64; ++i) s += v[i];
  int incl = s;
#pragma unroll
  for (int d = 1; d < 64; d <<= 1) {
    int n = __shfl_up(incl, d, 64);
    if (lane >= d) incl += n;
  }
  if (lane == 63) wsum[w] = incl;
  __syncthreads();
  if (t == 0) {
    int run = 0;
    for (int i = 0; i < 4; ++i) { int x = wsum[i]; wpre[i] = run; run += x; }
  }
  __syncthreads();
  int run = incl - s + wpre[w];
#pragma unroll
  for (int i = 0; i < 16; ++i) {
    int4 o;
    o.x = run; run += v[i * 4 + 0];
    o.y = run; run += v[i * 4 + 1];
    o.z = run; run += v[i * 4 + 2];
    o.w = run; run += v[i * 4 + 3];
    reinterpret_cast<int4*>(off)[t * 16 + i] = o;
    reinterpret_cast<int4*>(cur)[t * 16 + i] = o;
  }
  if (t == 255) off[NN] = run;   // == NE
}

__global__ __launch_bounds__(256) void scatter_edges(const int* __restrict__ src,
                                                     const int* __restrict__ dst,
                                                     const float* __restrict__ w,
                                                     int* __restrict__ cur,
                                                     int* __restrict__ sdst,
                                                     float* __restrict__ sw) {
  int e = blockIdx.x * 256 + threadIdx.x;
  if (e < NE) {
    int s = src[e];
    int p = atomicAdd(&cur[s], 1);
    sdst[p] = dst[e];
    sw[p] = w[e];
  }
}

// ---------------- fused: h = spmm(H0); G = h @ [W2|W3] ----------------
__global__ __launch_bounds__(256) void spmm_g(const int* __restrict__ off,
                                              const int* __restrict__ sdst,
                                              const float* __restrict__ sw,
                                              const float* __restrict__ Hin,
                                              const float* __restrict__ W2,
                                              const float* __restrict__ W3,
                                              float* __restrict__ G) {
  __shared__ float wsh[64][64];   // cols 0-31 = W2, 32-63 = W3
  __shared__ float hsh[4][64];
  const int t = threadIdx.x;
  for (int i = t; i < 64 * 32; i += 256) {
    int k = i >> 5, c = i & 31;
    wsh[k][c]      = W2[i];
    wsh[k][c + 32] = W3[i];
  }
  const int node = blockIdx.x * 4 + (t >> 6);
  const int lane = t & 63;
  const int beg = off[node], end = off[node + 1];
  float acc = 0.f;
  int e = beg;
  for (; e + 4 <= end; e += 4) {
    int d0 = sdst[e], d1 = sdst[e + 1], d2 = sdst[e + 2], d3 = sdst[e + 3];
    float w0 = sw[e], w1 = sw[e + 1], w2 = sw[e + 2], w3 = sw[e + 3];
    acc += w0 * Hin[(size_t)d0 * 64 + lane];
    acc += w1 * Hin[(size_t)d1 * 64 + lane];
    acc += w2 * Hin[(size_t)d2 * 64 + lane];
    acc += w3 * Hin[(size_t)d3 * 64 + lane];
  }
  for (; e < end; ++e) acc += sw[e] * Hin[(size_t)sdst[e] * 64 + lane];
  hsh[t >> 6][lane] = acc;
  __syncthreads();
  float g = 0.f;
#pragma unroll
  for (int k = 0; k < 64; ++k) g += hsh[t >> 6][k] * wsh[k][lane];
  G[(size_t)node * 64 + lane] = g;
}

// ---------------- fused: [zmean|zlog] = spmm(G); ztb = ((zmean*R)@M)*R ----------------
__global__ __launch_bounds__(256) void spmm_zt(const int* __restrict__ off,
                                               const int* __restrict__ sdst,
                                               const float* __restrict__ sw,
                                               const float* __restrict__ G,
                                               const float* __restrict__ R,
                                               const float* __restrict__ M,
                                               float* __restrict__ zmean,
                                               float* __restrict__ zlog,
                                               __hip_bfloat16* __restrict__ ztb) {
  __shared__ float Ms[32][33];
  __shared__ float zr[4][32];
  const int t = threadIdx.x;
  for (int i = t; i < 1024; i += 256) Ms[i >> 5][i & 31] = M[i];
  const int wv = t >> 6, lane = t & 63;
  const int node = blockIdx.x * 4 + wv;
  const int beg = off[node], end = off[node + 1];
  float acc = 0.f;
  int e = beg;
  for (; e + 4 <= end; e += 4) {
    int d0 = sdst[e], d1 = sdst[e + 1], d2 = sdst[e + 2], d3 = sdst[e + 3];
    float w0 = sw[e], w1 = sw[e + 1], w2 = sw[e + 2], w3 = sw[e + 3];
    acc += w0 * G[(size_t)d0 * 64 + lane];
    acc += w1 * G[(size_t)d1 * 64 + lane];
    acc += w2 * G[(size_t)d2 * 64 + lane];
    acc += w3 * G[(size_t)d3 * 64 + lane];
  }
  for (; e < end; ++e) acc += sw[e] * G[(size_t)sdst[e] * 64 + lane];
  if (lane < 32) {
    zmean[(size_t)node * 32 + lane] = acc;
    zr[wv][lane] = acc * R[lane];
  } else {
    zlog[(size_t)node * 32 + (lane - 32)] = acc;
  }
  __syncthreads();
  if (lane < 32) {
    float zt = 0.f;
#pragma unroll
    for (int k = 0; k < 32; ++k) zt += zr[wv][k] * Ms[k][lane];
    ztb[(size_t)node * 32 + lane] = __float2bfloat16(zt * R[lane]);
  }
}

// ---------------- adj = zt @ zt^T ----------------
// Long-stream structure: block = 16-row band x ALL 16384 cols (grid 1024,
// 2 blocks/CU). Double-buffered LDS [2][16][512] (64 KB). Per 512-col
// supertile s: fill(s+1) into buf[(s+1)&1] (8 MFMAs/wave, swizzled
// ds_writes) is issued TOGETHER with store(s) from buf[s&1] (wave w owns
// rows 4w..4w+3; per row 2 sequential 1 KB single-segment NT stores),
// then ONE barrier. Each row = one 64 KB logically-sequential stream;
// ~2048 instantaneous streams chip-wide = the fill kernel's profile.
__global__ __launch_bounds__(256) void adj_mfma(const __hip_bfloat16* __restrict__ ztb,
                                                float* __restrict__ adj) {
  __shared__ float buf[2][16][512];            // 64 KB
  const int t = threadIdx.x;
  const int wave = t >> 6;
  const int lane = t & 63;
  const int l15 = lane & 15;
  const int kblk = lane >> 4;                  // 0..3
  const int rbase = blockIdx.x * 16;
  const short* zs = reinterpret_cast<const short*>(ztb);

  // B fragment (the band's 16 output rows): B[k][j] = zt[rbase+j][k]
  bf16x8 b0 = *reinterpret_cast<const bf16x8*>(&zs[(size_t)(rbase + l15) * 32 + kblk * 8]);

  // ---- fill supertile s into buf[s&1] ----
  auto fill = [&](int s) {
    const int c0 = s * 512;
#pragma unroll
    for (int tc = 0; tc < 8; ++tc) {
      const int acol = c0 + wave * 128 + tc * 16 + l15;
      bf16x8 a = *reinterpret_cast<const bf16x8*>(&zs[(size_t)acol * 32 + kblk * 8]);
      f32x4 z4 = {0.f, 0.f, 0.f, 0.f};
      f32x4 d = __builtin_amdgcn_mfma_f32_16x16x32_bf16(a, b0, z4, 0, 0, 0);
      const int u = wave * 32 + tc * 4 + kblk;   // logical 16B unit in [0,128)
      const int pu = u ^ (l15 & 7);              // swizzle
      *reinterpret_cast<f32x4*>(&buf[s & 1][l15][pu * 4]) = d;
    }
  };
  // ---- store supertile s from buf[s&1] ----
  auto store = [&](int s) {
    const int c0 = s * 512;
#pragma unroll
    for (int rr = 0; rr < 4; ++rr) {
      const int row = wave * 4 + rr;
      float* dst = &adj[(size_t)(rbase + row) * NN + c0];
#pragma unroll
      for (int seg = 0; seg < 2; ++seg) {
        const int u = seg * 64 + lane;           // logical 16B unit
        const int pu = u ^ (row & 7);            // inverse swizzle
        f32x4 v = *reinterpret_cast<const f32x4*>(&buf[s & 1][row][pu * 4]);
        __builtin_nontemporal_store(
            v, reinterpret_cast<f32x4*>(dst + seg * 256 + lane * 4));
      }
    }
  };

  fill(0);
  __syncthreads();
  for (int s = 0; s < 32; ++s) {
    if (s + 1 < 32) fill(s + 1);   // independent of store(s): different buffer
    store(s);
    __syncthreads();
  }
}

// ---------------- launcher ----------------
extern "C" void kernel_launch(void* const* d_in, const int* in_sizes, int n_in,
                              void* d_out, int out_size, void* d_ws, size_t ws_size,
                              hipStream_t stream) {
  (void)in_sizes; (void)n_in; (void)out_size; (void)ws_size;

  const float* x   = (const float*)d_in[0];
  const float* ew  = (const float*)d_in[1];
  const float* W1  = (const float*)d_in[2];
  const float* W2  = (const float*)d_in[3];
  const float* W3  = (const float*)d_in[4];
  const float* R   = (const float*)d_in[5];
  const float* M   = (const float*)d_in[6];
  const int* esrc  = (const int*)d_in[7];
  const int* edst  = (const int*)d_in[8];

  float* adj_out   = (float*)d_out;
  float* zmean_out = adj_out + (size_t)NN * NN;
  float* zlog_out  = zmean_out + (size_t)NN * HH2;

  char* p = (char*)d_ws;
  float* H0 = (float*)p;                 p += (size_t)NN * HH1 * 4;   // 4 MB
  float* G  = (float*)p;                 p += (size_t)NN * HH1 * 4;   // 4 MB
  __hip_bfloat16* ztb = (__hip_bfloat16*)p; p += (size_t)NN * HH2 * 2; // 1 MB
  int* cnt  = (int*)p;                   p += (size_t)NN * 4;
  int* off  = (int*)p;                   p += (size_t)(NN + 4) * 4;
  int* cur  = (int*)p;                   p += (size_t)NN * 4;
  int* sdst = (int*)p;                   p += (size_t)NE * 4;         // 2 MB
  float* sw = (float*)p;                 p += (size_t)NE * 4;         // 2 MB

  gemm_xw1_zero<<<320, 256, 0, stream>>>(x, W1, H0, cnt);
  hist_src<<<NE / 256, 256, 0, stream>>>(esrc, cnt);
  scan_offsets<<<1, 256, 0, stream>>>(cnt, off, cur);
  scatter_edges<<<NE / 256, 256, 0, stream>>>(esrc, edst, ew, cur, sdst, sw);
  spmm_g<<<NN / 4, 256, 0, stream>>>(off, sdst, sw, H0, W2, W3, G);
  spmm_zt<<<NN / 4, 256, 0, stream>>>(off, sdst, sw, G, R, M,
                                      zmean_out, zlog_out, ztb);

  adj_mfma<<<NN / 16, 256, 0, stream>>>(ztb, adj_out);
}

// Round 12
// 292.352 us; speedup vs baseline: 1.1748x; 1.1748x over previous
//
#include <hip/hip_runtime.h>
#include <hip/hip_bf16.h>

#define NN 16384
#define NE 524288
#define FIN 256
#define HH1 64
#define HH2 32

typedef __attribute__((ext_vector_type(8))) short bf16x8;
typedef __attribute__((ext_vector_type(4))) float f32x4;

// ---------------- H0 = x @ W1; trailing blocks zero cnt ----------------
__global__ __launch_bounds__(256) void gemm_xw1_zero(const float* __restrict__ x,
                                                     const float* __restrict__ W1,
                                                     float* __restrict__ H0,
                                                     int* __restrict__ cnt) {
  if (blockIdx.x >= 256) {                       // 64 trailing blocks: zero cnt[16384]
    int i = (blockIdx.x - 256) * 256 + threadIdx.x;
    cnt[i] = 0;
    return;
  }
  __shared__ float xs[64][65];
  __shared__ float ws[64][65];
  const int t = threadIdx.x;
  const int row0 = blockIdx.x * 64;
  const int tr = t >> 4, tc = t & 15;
  float acc[4][4] = {};
  for (int kc = 0; kc < FIN; kc += 64) {
#pragma unroll
    for (int i = 0; i < 4; ++i) {
      int slot = t + i * 256;
      int r = slot >> 4, c4 = (slot & 15) * 4;
      float4 v = *reinterpret_cast<const float4*>(&x[(size_t)(row0 + r) * FIN + kc + c4]);
      xs[r][c4 + 0] = v.x; xs[r][c4 + 1] = v.y; xs[r][c4 + 2] = v.z; xs[r][c4 + 3] = v.w;
      float4 wv = *reinterpret_cast<const float4*>(&W1[(size_t)(kc + r) * HH1 + c4]);
      ws[r][c4 + 0] = wv.x; ws[r][c4 + 1] = wv.y; ws[r][c4 + 2] = wv.z; ws[r][c4 + 3] = wv.w;
    }
    __syncthreads();
#pragma unroll
    for (int k = 0; k < 64; ++k) {
      float a[4], b[4];
#pragma unroll
      for (int i = 0; i < 4; ++i) a[i] = xs[tr * 4 + i][k];
#pragma unroll
      for (int j = 0; j < 4; ++j) b[j] = ws[k][tc * 4 + j];
#pragma unroll
      for (int i = 0; i < 4; ++i)
#pragma unroll
        for (int j = 0; j < 4; ++j) acc[i][j] += a[i] * b[j];
    }
    __syncthreads();
  }
#pragma unroll
  for (int i = 0; i < 4; ++i) {
    float4 o; o.x = acc[i][0]; o.y = acc[i][1]; o.z = acc[i][2]; o.w = acc[i][3];
    *reinterpret_cast<float4*>(&H0[(size_t)(row0 + tr * 4 + i) * HH1 + tc * 4]) = o;
  }
}

// ---------------- counting sort of edges by src ----------------
__global__ __launch_bounds__(256) void hist_src(const int* __restrict__ src,
                                                int* __restrict__ cnt) {
  int e = blockIdx.x * 256 + threadIdx.x;
  if (e < NE) atomicAdd(&cnt[src[e]], 1);
}

// single block, 256 threads: vector loads + shuffle scan
__global__ __launch_bounds__(256) void scan_offsets(const int* __restrict__ cnt,
                                                    int* __restrict__ off,
                                                    int* __restrict__ cur) {
  __shared__ int wsum[4];
  __shared__ int wpre[4];
  const int t = threadIdx.x;
  const int lane = t & 63, w = t >> 6;
  int v[64];
#pragma unroll
  for (int i = 0; i < 16; ++i) {
    int4 q = reinterpret_cast<const int4*>(cnt)[t * 16 + i];
    v[i * 4 + 0] = q.x; v[i * 4 + 1] = q.y; v[i * 4 + 2] = q.z; v[i * 4 + 3] = q.w;
  }
  int s = 0;
#pragma unroll
  for (int i = 0; i < 64; ++i) s += v[i];
  int incl = s;
#pragma unroll
  for (int d = 1; d < 64; d <<= 1) {
    int n = __shfl_up(incl, d, 64);
    if (lane >= d) incl += n;
  }
  if (lane == 63) wsum[w] = incl;
  __syncthreads();
  if (t == 0) {
    int run = 0;
    for (int i = 0; i < 4; ++i) { int x = wsum[i]; wpre[i] = run; run += x; }
  }
  __syncthreads();
  int run = incl - s + wpre[w];
#pragma unroll
  for (int i = 0; i < 16; ++i) {
    int4 o;
    o.x = run; run += v[i * 4 + 0];
    o.y = run; run += v[i * 4 + 1];
    o.z = run; run += v[i * 4 + 2];
    o.w = run; run += v[i * 4 + 3];
    reinterpret_cast<int4*>(off)[t * 16 + i] = o;
    reinterpret_cast<int4*>(cur)[t * 16 + i] = o;
  }
  if (t == 255) off[NN] = run;   // == NE
}

__global__ __launch_bounds__(256) void scatter_edges(const int* __restrict__ src,
                                                     const int* __restrict__ dst,
                                                     const float* __restrict__ w,
                                                     int* __restrict__ cur,
                                                     int* __restrict__ sdst,
                                                     float* __restrict__ sw) {
  int e = blockIdx.x * 256 + threadIdx.x;
  if (e < NE) {
    int s = src[e];
    int p = atomicAdd(&cur[s], 1);
    sdst[p] = dst[e];
    sw[p] = w[e];
  }
}

// ---------------- fused: h = spmm(H0); G = h @ [W2|W3] ----------------
__global__ __launch_bounds__(256) void spmm_g(const int* __restrict__ off,
                                              const int* __restrict__ sdst,
                                              const float* __restrict__ sw,
                                              const float* __restrict__ Hin,
                                              const float* __restrict__ W2,
                                              const float* __restrict__ W3,
                                              float* __restrict__ G) {
  __shared__ float wsh[64][64];   // cols 0-31 = W2, 32-63 = W3
  __shared__ float hsh[4][64];
  const int t = threadIdx.x;
  for (int i = t; i < 64 * 32; i += 256) {
    int k = i >> 5, c = i & 31;
    wsh[k][c]      = W2[i];
    wsh[k][c + 32] = W3[i];
  }
  const int node = blockIdx.x * 4 + (t >> 6);
  const int lane = t & 63;
  const int beg = off[node], end = off[node + 1];
  float acc = 0.f;
  int e = beg;
  for (; e + 4 <= end; e += 4) {
    int d0 = sdst[e], d1 = sdst[e + 1], d2 = sdst[e + 2], d3 = sdst[e + 3];
    float w0 = sw[e], w1 = sw[e + 1], w2 = sw[e + 2], w3 = sw[e + 3];
    acc += w0 * Hin[(size_t)d0 * 64 + lane];
    acc += w1 * Hin[(size_t)d1 * 64 + lane];
    acc += w2 * Hin[(size_t)d2 * 64 + lane];
    acc += w3 * Hin[(size_t)d3 * 64 + lane];
  }
  for (; e < end; ++e) acc += sw[e] * Hin[(size_t)sdst[e] * 64 + lane];
  hsh[t >> 6][lane] = acc;
  __syncthreads();
  float g = 0.f;
#pragma unroll
  for (int k = 0; k < 64; ++k) g += hsh[t >> 6][k] * wsh[k][lane];
  G[(size_t)node * 64 + lane] = g;
}

// ---------------- fused: [zmean|zlog] = spmm(G); ztb = ((zmean*R)@M)*R ----------------
__global__ __launch_bounds__(256) void spmm_zt(const int* __restrict__ off,
                                               const int* __restrict__ sdst,
                                               const float* __restrict__ sw,
                                               const float* __restrict__ G,
                                               const float* __restrict__ R,
                                               const float* __restrict__ M,
                                               float* __restrict__ zmean,
                                               float* __restrict__ zlog,
                                               __hip_bfloat16* __restrict__ ztb) {
  __shared__ float Ms[32][33];
  __shared__ float zr[4][32];
  const int t = threadIdx.x;
  for (int i = t; i < 1024; i += 256) Ms[i >> 5][i & 31] = M[i];
  const int wv = t >> 6, lane = t & 63;
  const int node = blockIdx.x * 4 + wv;
  const int beg = off[node], end = off[node + 1];
  float acc = 0.f;
  int e = beg;
  for (; e + 4 <= end; e += 4) {
    int d0 = sdst[e], d1 = sdst[e + 1], d2 = sdst[e + 2], d3 = sdst[e + 3];
    float w0 = sw[e], w1 = sw[e + 1], w2 = sw[e + 2], w3 = sw[e + 3];
    acc += w0 * G[(size_t)d0 * 64 + lane];
    acc += w1 * G[(size_t)d1 * 64 + lane];
    acc += w2 * G[(size_t)d2 * 64 + lane];
    acc += w3 * G[(size_t)d3 * 64 + lane];
  }
  for (; e < end; ++e) acc += sw[e] * G[(size_t)sdst[e] * 64 + lane];
  if (lane < 32) {
    zmean[(size_t)node * 32 + lane] = acc;
    zr[wv][lane] = acc * R[lane];
  } else {
    zlog[(size_t)node * 32 + (lane - 32)] = acc;
  }
  __syncthreads();
  if (lane < 32) {
    float zt = 0.f;
#pragma unroll
    for (int k = 0; k < 32; ++k) zt += zr[wv][k] * Ms[k][lane];
    ztb[(size_t)node * 32 + lane] = __float2bfloat16(zt * R[lane]);
  }
}

// ---------------- adj = zt @ zt^T ----------------
// R8 structure (best: 297.6 us) + intra-block half pipelining.
// Block = 16 rows x 1024 cols (grid 16x1024, short blocks, 64 KB LDS,
// 2 blocks/CU). The tile is processed as two 512-col halves:
//   fill(0); bar; store(0); fill(1); bar; store(1)
// store(0) is issued BEFORE fill(1)'s MFMAs, so its HBM drain overlaps
// the second half's compute. Per row the two halves write 2 KB + 2 KB at
// consecutive addresses = same 4 KB sequential run as R8.
// Stores: 1 KB single-segment (64 lanes x 16 B) nontemporal, sequential.
__global__ __launch_bounds__(256) void adj_mfma(const __hip_bfloat16* __restrict__ ztb,
                                                float* __restrict__ adj) {
  __shared__ float tile[16][1024];             // 64 KB
  const int t = threadIdx.x;
  const int wave = t >> 6;
  const int lane = t & 63;
  const int l15 = lane & 15;
  const int kblk = lane >> 4;                  // 0..3
  const int rbase = blockIdx.y * 16;
  const int cbase = blockIdx.x * 1024;
  const short* zs = reinterpret_cast<const short*>(ztb);

  // B fragment (the band's 16 output rows): B[k][j] = zt[rbase+j][k]
  bf16x8 b0 = *reinterpret_cast<const bf16x8*>(&zs[(size_t)(rbase + l15) * 32 + kblk * 8]);

  // fill half h: wave covers cols [cbase + h*512 + wave*128, +128) = 8 MFMA tiles
  auto fill = [&](int h) {
#pragma unroll
    for (int tc = 0; tc < 8; ++tc) {
      const int acol = cbase + h * 512 + wave * 128 + tc * 16 + l15;
      bf16x8 a = *reinterpret_cast<const bf16x8*>(&zs[(size_t)acol * 32 + kblk * 8]);
      f32x4 z4 = {0.f, 0.f, 0.f, 0.f};
      f32x4 d = __builtin_amdgcn_mfma_f32_16x16x32_bf16(a, b0, z4, 0, 0, 0);
      const int u = h * 128 + wave * 32 + tc * 4 + kblk;  // 16B unit in [0,256)
      const int pu = u ^ (l15 & 7);                       // swizzle (low 3 bits)
      *reinterpret_cast<f32x4*>(&tile[l15][pu * 4]) = d;
    }
  };
  // store half h: wave w owns rows 4w..4w+3; per row 2 sequential 1KB stores
  auto store_h = [&](int h) {
#pragma unroll
    for (int rr = 0; rr < 4; ++rr) {
      const int row = wave * 4 + rr;
      float* dst = &adj[(size_t)(rbase + row) * NN + cbase + h * 512];
#pragma unroll
      for (int seg = 0; seg < 2; ++seg) {
        const int u = h * 128 + seg * 64 + lane;
        const int pu = u ^ (row & 7);                     // inverse swizzle
        f32x4 v = *reinterpret_cast<const f32x4*>(&tile[row][pu * 4]);
        __builtin_nontemporal_store(
            v, reinterpret_cast<f32x4*>(dst + seg * 256 + lane * 4));
      }
    }
  };

  fill(0);
  __syncthreads();
  store_h(0);      // stores issue first; drain overlaps fill(1)'s MFMAs
  fill(1);
  __syncthreads();
  store_h(1);
}

// ---------------- launcher ----------------
extern "C" void kernel_launch(void* const* d_in, const int* in_sizes, int n_in,
                              void* d_out, int out_size, void* d_ws, size_t ws_size,
                              hipStream_t stream) {
  (void)in_sizes; (void)n_in; (void)out_size; (void)ws_size;

  const float* x   = (const float*)d_in[0];
  const float* ew  = (const float*)d_in[1];
  const float* W1  = (const float*)d_in[2];
  const float* W2  = (const float*)d_in[3];
  const float* W3  = (const float*)d_in[4];
  const float* R   = (const float*)d_in[5];
  const float* M   = (const float*)d_in[6];
  const int* esrc  = (const int*)d_in[7];
  const int* edst  = (const int*)d_in[8];

  float* adj_out   = (float*)d_out;
  float* zmean_out = adj_out + (size_t)NN * NN;
  float* zlog_out  = zmean_out + (size_t)NN * HH2;

  char* p = (char*)d_ws;
  float* H0 = (float*)p;                 p += (size_t)NN * HH1 * 4;   // 4 MB
  float* G  = (float*)p;                 p += (size_t)NN * HH1 * 4;   // 4 MB
  __hip_bfloat16* ztb = (__hip_bfloat16*)p; p += (size_t)NN * HH2 * 2; // 1 MB
  int* cnt  = (int*)p;                   p += (size_t)NN * 4;
  int* off  = (int*)p;                   p += (size_t)(NN + 4) * 4;
  int* cur  = (int*)p;                   p += (size_t)NN * 4;
  int* sdst = (int*)p;                   p += (size_t)NE * 4;         // 2 MB
  float* sw = (float*)p;                 p += (size_t)NE * 4;         // 2 MB

  gemm_xw1_zero<<<320, 256, 0, stream>>>(x, W1, H0, cnt);
  hist_src<<<NE / 256, 256, 0, stream>>>(esrc, cnt);
  scan_offsets<<<1, 256, 0, stream>>>(cnt, off, cur);
  scatter_edges<<<NE / 256, 256, 0, stream>>>(esrc, edst, ew, cur, sdst, sw);
  spmm_g<<<NN / 4, 256, 0, stream>>>(off, sdst, sw, H0, W2, W3, G);
  spmm_zt<<<NN / 4, 256, 0, stream>>>(off, sdst, sw, G, R, M,
                                      zmean_out, zlog_out, ztb);

  dim3 g(NN / 1024, NN / 16, 1);
  adj_mfma<<<g, 256, 0, stream>>>(ztb, adj_out);
}

// Round 13
// 288.980 us; speedup vs baseline: 1.1885x; 1.0117x over previous
//
#include <hip/hip_runtime.h>
#include <hip/hip_bf16.h>

#define NN 16384
#define NE 524288
#define FIN 256
#define HH1 64
#define HH2 32

typedef __attribute__((ext_vector_type(8))) short bf16x8;
typedef __attribute__((ext_vector_type(4))) float f32x4;

// ---------------- H0 = x @ W1; trailing blocks zero cnt ----------------
__global__ __launch_bounds__(256) void gemm_xw1_zero(const float* __restrict__ x,
                                                     const float* __restrict__ W1,
                                                     float* __restrict__ H0,
                                                     int* __restrict__ cnt) {
  if (blockIdx.x >= 256) {                       // 64 trailing blocks: zero cnt[16384]
    int i = (blockIdx.x - 256) * 256 + threadIdx.x;
    cnt[i] = 0;
    return;
  }
  __shared__ float xs[64][65];
  __shared__ float ws[64][65];
  const int t = threadIdx.x;
  const int row0 = blockIdx.x * 64;
  const int tr = t >> 4, tc = t & 15;
  float acc[4][4] = {};
  for (int kc = 0; kc < FIN; kc += 64) {
#pragma unroll
    for (int i = 0; i < 4; ++i) {
      int slot = t + i * 256;
      int r = slot >> 4, c4 = (slot & 15) * 4;
      float4 v = *reinterpret_cast<const float4*>(&x[(size_t)(row0 + r) * FIN + kc + c4]);
      xs[r][c4 + 0] = v.x; xs[r][c4 + 1] = v.y; xs[r][c4 + 2] = v.z; xs[r][c4 + 3] = v.w;
      float4 wv = *reinterpret_cast<const float4*>(&W1[(size_t)(kc + r) * HH1 + c4]);
      ws[r][c4 + 0] = wv.x; ws[r][c4 + 1] = wv.y; ws[r][c4 + 2] = wv.z; ws[r][c4 + 3] = wv.w;
    }
    __syncthreads();
#pragma unroll
    for (int k = 0; k < 64; ++k) {
      float a[4], b[4];
#pragma unroll
      for (int i = 0; i < 4; ++i) a[i] = xs[tr * 4 + i][k];
#pragma unroll
      for (int j = 0; j < 4; ++j) b[j] = ws[k][tc * 4 + j];
#pragma unroll
      for (int i = 0; i < 4; ++i)
#pragma unroll
        for (int j = 0; j < 4; ++j) acc[i][j] += a[i] * b[j];
    }
    __syncthreads();
  }
#pragma unroll
  for (int i = 0; i < 4; ++i) {
    float4 o; o.x = acc[i][0]; o.y = acc[i][1]; o.z = acc[i][2]; o.w = acc[i][3];
    *reinterpret_cast<float4*>(&H0[(size_t)(row0 + tr * 4 + i) * HH1 + tc * 4]) = o;
  }
}

// ---------------- counting sort of edges by src ----------------
__global__ __launch_bounds__(256) void hist_src(const int* __restrict__ src,
                                                int* __restrict__ cnt) {
  int e = blockIdx.x * 256 + threadIdx.x;
  if (e < NE) atomicAdd(&cnt[src[e]], 1);
}

// single block, 256 threads: vector loads + shuffle scan
__global__ __launch_bounds__(256) void scan_offsets(const int* __restrict__ cnt,
                                                    int* __restrict__ off,
                                                    int* __restrict__ cur) {
  __shared__ int wsum[4];
  __shared__ int wpre[4];
  const int t = threadIdx.x;
  const int lane = t & 63, w = t >> 6;
  int v[64];
#pragma unroll
  for (int i = 0; i < 16; ++i) {
    int4 q = reinterpret_cast<const int4*>(cnt)[t * 16 + i];
    v[i * 4 + 0] = q.x; v[i * 4 + 1] = q.y; v[i * 4 + 2] = q.z; v[i * 4 + 3] = q.w;
  }
  int s = 0;
#pragma unroll
  for (int i = 0; i < 64; ++i) s += v[i];
  int incl = s;
#pragma unroll
  for (int d = 1; d < 64; d <<= 1) {
    int n = __shfl_up(incl, d, 64);
    if (lane >= d) incl += n;
  }
  if (lane == 63) wsum[w] = incl;
  __syncthreads();
  if (t == 0) {
    int run = 0;
    for (int i = 0; i < 4; ++i) { int x = wsum[i]; wpre[i] = run; run += x; }
  }
  __syncthreads();
  int run = incl - s + wpre[w];
#pragma unroll
  for (int i = 0; i < 16; ++i) {
    int4 o;
    o.x = run; run += v[i * 4 + 0];
    o.y = run; run += v[i * 4 + 1];
    o.z = run; run += v[i * 4 + 2];
    o.w = run; run += v[i * 4 + 3];
    reinterpret_cast<int4*>(off)[t * 16 + i] = o;
    reinterpret_cast<int4*>(cur)[t * 16 + i] = o;
  }
  if (t == 255) off[NN] = run;   // == NE
}

__global__ __launch_bounds__(256) void scatter_edges(const int* __restrict__ src,
                                                     const int* __restrict__ dst,
                                                     const float* __restrict__ w,
                                                     int* __restrict__ cur,
                                                     int* __restrict__ sdst,
                                                     float* __restrict__ sw) {
  int e = blockIdx.x * 256 + threadIdx.x;
  if (e < NE) {
    int s = src[e];
    int p = atomicAdd(&cur[s], 1);
    sdst[p] = dst[e];
    sw[p] = w[e];
  }
}

// ---------------- fused: h = spmm(H0); G = h @ [W2|W3] ----------------
__global__ __launch_bounds__(256) void spmm_g(const int* __restrict__ off,
                                              const int* __restrict__ sdst,
                                              const float* __restrict__ sw,
                                              const float* __restrict__ Hin,
                                              const float* __restrict__ W2,
                                              const float* __restrict__ W3,
                                              float* __restrict__ G) {
  __shared__ float wsh[64][64];   // cols 0-31 = W2, 32-63 = W3
  __shared__ float hsh[4][64];
  const int t = threadIdx.x;
  for (int i = t; i < 64 * 32; i += 256) {
    int k = i >> 5, c = i & 31;
    wsh[k][c]      = W2[i];
    wsh[k][c + 32] = W3[i];
  }
  const int node = blockIdx.x * 4 + (t >> 6);
  const int lane = t & 63;
  const int beg = off[node], end = off[node + 1];
  float acc = 0.f;
  int e = beg;
  for (; e + 4 <= end; e += 4) {
    int d0 = sdst[e], d1 = sdst[e + 1], d2 = sdst[e + 2], d3 = sdst[e + 3];
    float w0 = sw[e], w1 = sw[e + 1], w2 = sw[e + 2], w3 = sw[e + 3];
    acc += w0 * Hin[(size_t)d0 * 64 + lane];
    acc += w1 * Hin[(size_t)d1 * 64 + lane];
    acc += w2 * Hin[(size_t)d2 * 64 + lane];
    acc += w3 * Hin[(size_t)d3 * 64 + lane];
  }
  for (; e < end; ++e) acc += sw[e] * Hin[(size_t)sdst[e] * 64 + lane];
  hsh[t >> 6][lane] = acc;
  __syncthreads();
  float g = 0.f;
#pragma unroll
  for (int k = 0; k < 64; ++k) g += hsh[t >> 6][k] * wsh[k][lane];
  G[(size_t)node * 64 + lane] = g;
}

// ---------------- fused: [zmean|zlog] = spmm(G); ztb = ((zmean*R)@M)*R ----------------
__global__ __launch_bounds__(256) void spmm_zt(const int* __restrict__ off,
                                               const int* __restrict__ sdst,
                                               const float* __restrict__ sw,
                                               const float* __restrict__ G,
                                               const float* __restrict__ R,
                                               const float* __restrict__ M,
                                               float* __restrict__ zmean,
                                               float* __restrict__ zlog,
                                               __hip_bfloat16* __restrict__ ztb) {
  __shared__ float Ms[32][33];
  __shared__ float zr[4][32];
  const int t = threadIdx.x;
  for (int i = t; i < 1024; i += 256) Ms[i >> 5][i & 31] = M[i];
  const int wv = t >> 6, lane = t & 63;
  const int node = blockIdx.x * 4 + wv;
  const int beg = off[node], end = off[node + 1];
  float acc = 0.f;
  int e = beg;
  for (; e + 4 <= end; e += 4) {
    int d0 = sdst[e], d1 = sdst[e + 1], d2 = sdst[e + 2], d3 = sdst[e + 3];
    float w0 = sw[e], w1 = sw[e + 1], w2 = sw[e + 2], w3 = sw[e + 3];
    acc += w0 * G[(size_t)d0 * 64 + lane];
    acc += w1 * G[(size_t)d1 * 64 + lane];
    acc += w2 * G[(size_t)d2 * 64 + lane];
    acc += w3 * G[(size_t)d3 * 64 + lane];
  }
  for (; e < end; ++e) acc += sw[e] * G[(size_t)sdst[e] * 64 + lane];
  if (lane < 32) {
    zmean[(size_t)node * 32 + lane] = acc;
    zr[wv][lane] = acc * R[lane];
  } else {
    zlog[(size_t)node * 32 + (lane - 32)] = acc;
  }
  __syncthreads();
  if (lane < 32) {
    float zt = 0.f;
#pragma unroll
    for (int k = 0; k < 32; ++k) zt += zr[wv][k] * Ms[k][lane];
    ztb[(size_t)node * 32 + lane] = __float2bfloat16(zt * R[lane]);
  }
}

// ---------------- adj = zt @ zt^T ----------------
// R11 structure with QUARTER-granularity pipelining (4 x 256-col stages):
//   fill(0); bar; store(0); fill(1); bar; store(1); ... store(3)
// Un-overlapped prologue shrinks from 1/2 to 1/4 of fill work; first
// stores issue earlier. Per row, stages write 1 KB each at consecutive
// addresses (same 4 KB sequential run; R11 proved mid-row pauses are ok).
// Block = 16 rows x 1024 cols, 64 KB LDS, 2 blocks/CU, grid 16x1024.
// Stores: 1 KB single-segment (64 lanes x 16 B) nontemporal.
__global__ __launch_bounds__(256) void adj_mfma(const __hip_bfloat16* __restrict__ ztb,
                                                float* __restrict__ adj) {
  __shared__ float tile[16][1024];             // 64 KB
  const int t = threadIdx.x;
  const int wave = t >> 6;
  const int lane = t & 63;
  const int l15 = lane & 15;
  const int kblk = lane >> 4;                  // 0..3
  const int rbase = blockIdx.y * 16;
  const int cbase = blockIdx.x * 1024;
  const short* zs = reinterpret_cast<const short*>(ztb);

  // B fragment (the band's 16 output rows): B[k][j] = zt[rbase+j][k]
  bf16x8 b0 = *reinterpret_cast<const bf16x8*>(&zs[(size_t)(rbase + l15) * 32 + kblk * 8]);

  // fill quarter q: wave covers cols [cbase + q*256 + wave*64, +64) = 4 tiles
  auto fill = [&](int q) {
#pragma unroll
    for (int tc = 0; tc < 4; ++tc) {
      const int acol = cbase + q * 256 + wave * 64 + tc * 16 + l15;
      bf16x8 a = *reinterpret_cast<const bf16x8*>(&zs[(size_t)acol * 32 + kblk * 8]);
      f32x4 z4 = {0.f, 0.f, 0.f, 0.f};
      f32x4 d = __builtin_amdgcn_mfma_f32_16x16x32_bf16(a, b0, z4, 0, 0, 0);
      const int u = q * 64 + wave * 16 + tc * 4 + kblk;   // 16B unit in [0,256)
      const int pu = u ^ (l15 & 7);                       // swizzle (low 3 bits)
      *reinterpret_cast<f32x4*>(&tile[l15][pu * 4]) = d;
    }
  };
  // store quarter q: wave w owns rows 4w..4w+3; 1 KB single-segment per row
  auto store_q = [&](int q) {
#pragma unroll
    for (int rr = 0; rr < 4; ++rr) {
      const int row = wave * 4 + rr;
      const int u = q * 64 + lane;
      const int pu = u ^ (row & 7);                       // inverse swizzle
      f32x4 v = *reinterpret_cast<const f32x4*>(&tile[row][pu * 4]);
      __builtin_nontemporal_store(
          v, reinterpret_cast<f32x4*>(&adj[(size_t)(rbase + row) * NN + cbase +
                                           q * 256 + lane * 4]));
    }
  };

  fill(0);
  __syncthreads();
  store_q(0);
  fill(1);
  __syncthreads();
  store_q(1);
  fill(2);
  __syncthreads();
  store_q(2);
  fill(3);
  __syncthreads();
  store_q(3);
}

// ---------------- launcher ----------------
extern "C" void kernel_launch(void* const* d_in, const int* in_sizes, int n_in,
                              void* d_out, int out_size, void* d_ws, size_t ws_size,
                              hipStream_t stream) {
  (void)in_sizes; (void)n_in; (void)out_size; (void)ws_size;

  const float* x   = (const float*)d_in[0];
  const float* ew  = (const float*)d_in[1];
  const float* W1  = (const float*)d_in[2];
  const float* W2  = (const float*)d_in[3];
  const float* W3  = (const float*)d_in[4];
  const float* R   = (const float*)d_in[5];
  const float* M   = (const float*)d_in[6];
  const int* esrc  = (const int*)d_in[7];
  const int* edst  = (const int*)d_in[8];

  float* adj_out   = (float*)d_out;
  float* zmean_out = adj_out + (size_t)NN * NN;
  float* zlog_out  = zmean_out + (size_t)NN * HH2;

  char* p = (char*)d_ws;
  float* H0 = (float*)p;                 p += (size_t)NN * HH1 * 4;   // 4 MB
  float* G  = (float*)p;                 p += (size_t)NN * HH1 * 4;   // 4 MB
  __hip_bfloat16* ztb = (__hip_bfloat16*)p; p += (size_t)NN * HH2 * 2; // 1 MB
  int* cnt  = (int*)p;                   p += (size_t)NN * 4;
  int* off  = (int*)p;                   p += (size_t)(NN + 4) * 4;
  int* cur  = (int*)p;                   p += (size_t)NN * 4;
  int* sdst = (int*)p;                   p += (size_t)NE * 4;         // 2 MB
  float* sw = (float*)p;                 p += (size_t)NE * 4;         // 2 MB

  gemm_xw1_zero<<<320, 256, 0, stream>>>(x, W1, H0, cnt);
  hist_src<<<NE / 256, 256, 0, stream>>>(esrc, cnt);
  scan_offsets<<<1, 256, 0, stream>>>(cnt, off, cur);
  scatter_edges<<<NE / 256, 256, 0, stream>>>(esrc, edst, ew, cur, sdst, sw);
  spmm_g<<<NN / 4, 256, 0, stream>>>(off, sdst, sw, H0, W2, W3, G);
  spmm_zt<<<NN / 4, 256, 0, stream>>>(off, sdst, sw, G, R, M,
                                      zmean_out, zlog_out, ztb);

  dim3 g(NN / 1024, NN / 16, 1);
  adj_mfma<<<g, 256, 0, stream>>>(ztb, adj_out);
}

// Round 14
// 286.023 us; speedup vs baseline: 1.2008x; 1.0103x over previous
//
#include <hip/hip_runtime.h>
#include <hip/hip_bf16.h>

#define NN 16384
#define NE 524288
#define FIN 256
#define HH1 64
#define HH2 32

typedef __attribute__((ext_vector_type(8))) short bf16x8;
typedef __attribute__((ext_vector_type(4))) float f32x4;

__device__ __forceinline__ float bf2f(unsigned short u) {
  unsigned int x = ((unsigned int)u) << 16;
  return __uint_as_float(x);
}
__device__ __forceinline__ unsigned short f2bf(float f) {
  unsigned int x = __float_as_uint(f);
  unsigned int r = (x + 0x7FFF + ((x >> 16) & 1)) >> 16;   // RNE
  return (unsigned short)r;
}

// ---------------- H0(bf16) = x @ W1; trailing blocks zero cnt ----------------
__global__ __launch_bounds__(256) void gemm_xw1_zero(const float* __restrict__ x,
                                                     const float* __restrict__ W1,
                                                     unsigned short* __restrict__ H0,
                                                     int* __restrict__ cnt) {
  if (blockIdx.x >= 256) {                       // 64 trailing blocks: zero cnt[16384]
    int i = (blockIdx.x - 256) * 256 + threadIdx.x;
    cnt[i] = 0;
    return;
  }
  __shared__ float xs[64][65];
  __shared__ float ws[64][65];
  const int t = threadIdx.x;
  const int row0 = blockIdx.x * 64;
  const int tr = t >> 4, tc = t & 15;
  float acc[4][4] = {};
  for (int kc = 0; kc < FIN; kc += 64) {
#pragma unroll
    for (int i = 0; i < 4; ++i) {
      int slot = t + i * 256;
      int r = slot >> 4, c4 = (slot & 15) * 4;
      float4 v = *reinterpret_cast<const float4*>(&x[(size_t)(row0 + r) * FIN + kc + c4]);
      xs[r][c4 + 0] = v.x; xs[r][c4 + 1] = v.y; xs[r][c4 + 2] = v.z; xs[r][c4 + 3] = v.w;
      float4 wv = *reinterpret_cast<const float4*>(&W1[(size_t)(kc + r) * HH1 + c4]);
      ws[r][c4 + 0] = wv.x; ws[r][c4 + 1] = wv.y; ws[r][c4 + 2] = wv.z; ws[r][c4 + 3] = wv.w;
    }
    __syncthreads();
#pragma unroll
    for (int k = 0; k < 64; ++k) {
      float a[4], b[4];
#pragma unroll
      for (int i = 0; i < 4; ++i) a[i] = xs[tr * 4 + i][k];
#pragma unroll
      for (int j = 0; j < 4; ++j) b[j] = ws[k][tc * 4 + j];
#pragma unroll
      for (int i = 0; i < 4; ++i)
#pragma unroll
        for (int j = 0; j < 4; ++j) acc[i][j] += a[i] * b[j];
    }
    __syncthreads();
  }
#pragma unroll
  for (int i = 0; i < 4; ++i) {
    ushort4 o;
    o.x = f2bf(acc[i][0]); o.y = f2bf(acc[i][1]);
    o.z = f2bf(acc[i][2]); o.w = f2bf(acc[i][3]);
    *reinterpret_cast<ushort4*>(&H0[(size_t)(row0 + tr * 4 + i) * HH1 + tc * 4]) = o;
  }
}

// ---------------- counting sort of edges by src ----------------
__global__ __launch_bounds__(256) void hist_src(const int* __restrict__ src,
                                                int* __restrict__ cnt) {
  int e = blockIdx.x * 256 + threadIdx.x;
  if (e < NE) atomicAdd(&cnt[src[e]], 1);
}

// single block, 256 threads: vector loads + shuffle scan
__global__ __launch_bounds__(256) void scan_offsets(const int* __restrict__ cnt,
                                                    int* __restrict__ off,
                                                    int* __restrict__ cur) {
  __shared__ int wsum[4];
  __shared__ int wpre[4];
  const int t = threadIdx.x;
  const int lane = t & 63, w = t >> 6;
  int v[64];
#pragma unroll
  for (int i = 0; i < 16; ++i) {
    int4 q = reinterpret_cast<const int4*>(cnt)[t * 16 + i];
    v[i * 4 + 0] = q.x; v[i * 4 + 1] = q.y; v[i * 4 + 2] = q.z; v[i * 4 + 3] = q.w;
  }
  int s = 0;
#pragma unroll
  for (int i = 0; i < 64; ++i) s += v[i];
  int incl = s;
#pragma unroll
  for (int d = 1; d < 64; d <<= 1) {
    int n = __shfl_up(incl, d, 64);
    if (lane >= d) incl += n;
  }
  if (lane == 63) wsum[w] = incl;
  __syncthreads();
  if (t == 0) {
    int run = 0;
    for (int i = 0; i < 4; ++i) { int x = wsum[i]; wpre[i] = run; run += x; }
  }
  __syncthreads();
  int run = incl - s + wpre[w];
#pragma unroll
  for (int i = 0; i < 16; ++i) {
    int4 o;
    o.x = run; run += v[i * 4 + 0];
    o.y = run; run += v[i * 4 + 1];
    o.z = run; run += v[i * 4 + 2];
    o.w = run; run += v[i * 4 + 3];
    reinterpret_cast<int4*>(off)[t * 16 + i] = o;
    reinterpret_cast<int4*>(cur)[t * 16 + i] = o;
  }
  if (t == 255) off[NN] = run;   // == NE
}

__global__ __launch_bounds__(256) void scatter_edges(const int* __restrict__ src,
                                                     const int* __restrict__ dst,
                                                     const float* __restrict__ w,
                                                     int* __restrict__ cur,
                                                     int* __restrict__ sdst,
                                                     float* __restrict__ sw) {
  int e = blockIdx.x * 256 + threadIdx.x;
  if (e < NE) {
    int s = src[e];
    int p = atomicAdd(&cur[s], 1);
    sdst[p] = dst[e];
    sw[p] = w[e];
  }
}

// ---------------- fused: h = spmm(H0 bf16); G(bf16) = h @ [W2|W3] ----------------
__global__ __launch_bounds__(256) void spmm_g(const int* __restrict__ off,
                                              const int* __restrict__ sdst,
                                              const float* __restrict__ sw,
                                              const unsigned short* __restrict__ Hin,
                                              const float* __restrict__ W2,
                                              const float* __restrict__ W3,
                                              unsigned short* __restrict__ G) {
  __shared__ float wsh[64][64];   // cols 0-31 = W2, 32-63 = W3
  __shared__ float hsh[4][64];
  const int t = threadIdx.x;
  for (int i = t; i < 64 * 32; i += 256) {
    int k = i >> 5, c = i & 31;
    wsh[k][c]      = W2[i];
    wsh[k][c + 32] = W3[i];
  }
  const int node = blockIdx.x * 4 + (t >> 6);
  const int lane = t & 63;
  const int beg = off[node], end = off[node + 1];
  float acc = 0.f;
  int e = beg;
  for (; e + 4 <= end; e += 4) {
    int d0 = sdst[e], d1 = sdst[e + 1], d2 = sdst[e + 2], d3 = sdst[e + 3];
    float w0 = sw[e], w1 = sw[e + 1], w2 = sw[e + 2], w3 = sw[e + 3];
    acc += w0 * bf2f(Hin[(size_t)d0 * 64 + lane]);
    acc += w1 * bf2f(Hin[(size_t)d1 * 64 + lane]);
    acc += w2 * bf2f(Hin[(size_t)d2 * 64 + lane]);
    acc += w3 * bf2f(Hin[(size_t)d3 * 64 + lane]);
  }
  for (; e < end; ++e) acc += sw[e] * bf2f(Hin[(size_t)sdst[e] * 64 + lane]);
  hsh[t >> 6][lane] = acc;
  __syncthreads();
  float g = 0.f;
#pragma unroll
  for (int k = 0; k < 64; ++k) g += hsh[t >> 6][k] * wsh[k][lane];
  G[(size_t)node * 64 + lane] = f2bf(g);
}

// ---------------- fused: [zmean|zlog] = spmm(G bf16); ztb = ((zmean*R)@M)*R ----------------
__global__ __launch_bounds__(256) void spmm_zt(const int* __restrict__ off,
                                               const int* __restrict__ sdst,
                                               const float* __restrict__ sw,
                                               const unsigned short* __restrict__ G,
                                               const float* __restrict__ R,
                                               const float* __restrict__ M,
                                               float* __restrict__ zmean,
                                               float* __restrict__ zlog,
                                               __hip_bfloat16* __restrict__ ztb) {
  __shared__ float Ms[32][33];
  __shared__ float zr[4][32];
  const int t = threadIdx.x;
  for (int i = t; i < 1024; i += 256) Ms[i >> 5][i & 31] = M[i];
  const int wv = t >> 6, lane = t & 63;
  const int node = blockIdx.x * 4 + wv;
  const int beg = off[node], end = off[node + 1];
  float acc = 0.f;
  int e = beg;
  for (; e + 4 <= end; e += 4) {
    int d0 = sdst[e], d1 = sdst[e + 1], d2 = sdst[e + 2], d3 = sdst[e + 3];
    float w0 = sw[e], w1 = sw[e + 1], w2 = sw[e + 2], w3 = sw[e + 3];
    acc += w0 * bf2f(G[(size_t)d0 * 64 + lane]);
    acc += w1 * bf2f(G[(size_t)d1 * 64 + lane]);
    acc += w2 * bf2f(G[(size_t)d2 * 64 + lane]);
    acc += w3 * bf2f(G[(size_t)d3 * 64 + lane]);
  }
  for (; e < end; ++e) acc += sw[e] * bf2f(G[(size_t)sdst[e] * 64 + lane]);
  if (lane < 32) {
    zmean[(size_t)node * 32 + lane] = acc;
    zr[wv][lane] = acc * R[lane];
  } else {
    zlog[(size_t)node * 32 + (lane - 32)] = acc;
  }
  __syncthreads();
  if (lane < 32) {
    float zt = 0.f;
#pragma unroll
    for (int k = 0; k < 32; ++k) zt += zr[wv][k] * Ms[k][lane];
    ztb[(size_t)node * 32 + lane] = __float2bfloat16(zt * R[lane]);
  }
}

// ---------------- adj = zt @ zt^T (R12 verbatim) ----------------
__global__ __launch_bounds__(256) void adj_mfma(const __hip_bfloat16* __restrict__ ztb,
                                                float* __restrict__ adj) {
  __shared__ float tile[16][1024];             // 64 KB
  const int t = threadIdx.x;
  const int wave = t >> 6;
  const int lane = t & 63;
  const int l15 = lane & 15;
  const int kblk = lane >> 4;                  // 0..3
  const int rbase = blockIdx.y * 16;
  const int cbase = blockIdx.x * 1024;
  const short* zs = reinterpret_cast<const short*>(ztb);

  bf16x8 b0 = *reinterpret_cast<const bf16x8*>(&zs[(size_t)(rbase + l15) * 32 + kblk * 8]);

  auto fill = [&](int q) {
#pragma unroll
    for (int tc = 0; tc < 4; ++tc) {
      const int acol = cbase + q * 256 + wave * 64 + tc * 16 + l15;
      bf16x8 a = *reinterpret_cast<const bf16x8*>(&zs[(size_t)acol * 32 + kblk * 8]);
      f32x4 z4 = {0.f, 0.f, 0.f, 0.f};
      f32x4 d = __builtin_amdgcn_mfma_f32_16x16x32_bf16(a, b0, z4, 0, 0, 0);
      const int u = q * 64 + wave * 16 + tc * 4 + kblk;   // 16B unit in [0,256)
      const int pu = u ^ (l15 & 7);                       // swizzle (low 3 bits)
      *reinterpret_cast<f32x4*>(&tile[l15][pu * 4]) = d;
    }
  };
  auto store_q = [&](int q) {
#pragma unroll
    for (int rr = 0; rr < 4; ++rr) {
      const int row = wave * 4 + rr;
      const int u = q * 64 + lane;
      const int pu = u ^ (row & 7);                       // inverse swizzle
      f32x4 v = *reinterpret_cast<const f32x4*>(&tile[row][pu * 4]);
      __builtin_nontemporal_store(
          v, reinterpret_cast<f32x4*>(&adj[(size_t)(rbase + row) * NN + cbase +
                                           q * 256 + lane * 4]));
    }
  };

  fill(0);
  __syncthreads();
  store_q(0);
  fill(1);
  __syncthreads();
  store_q(1);
  fill(2);
  __syncthreads();
  store_q(2);
  fill(3);
  __syncthreads();
  store_q(3);
}

// ---------------- launcher ----------------
extern "C" void kernel_launch(void* const* d_in, const int* in_sizes, int n_in,
                              void* d_out, int out_size, void* d_ws, size_t ws_size,
                              hipStream_t stream) {
  (void)in_sizes; (void)n_in; (void)out_size; (void)ws_size;

  const float* x   = (const float*)d_in[0];
  const float* ew  = (const float*)d_in[1];
  const float* W1  = (const float*)d_in[2];
  const float* W2  = (const float*)d_in[3];
  const float* W3  = (const float*)d_in[4];
  const float* R   = (const float*)d_in[5];
  const float* M   = (const float*)d_in[6];
  const int* esrc  = (const int*)d_in[7];
  const int* edst  = (const int*)d_in[8];

  float* adj_out   = (float*)d_out;
  float* zmean_out = adj_out + (size_t)NN * NN;
  float* zlog_out  = zmean_out + (size_t)NN * HH2;

  char* p = (char*)d_ws;
  unsigned short* H0 = (unsigned short*)p; p += (size_t)NN * HH1 * 2;  // 2 MB bf16
  unsigned short* G  = (unsigned short*)p; p += (size_t)NN * HH1 * 2;  // 2 MB bf16
  __hip_bfloat16* ztb = (__hip_bfloat16*)p; p += (size_t)NN * HH2 * 2; // 1 MB
  int* cnt  = (int*)p;                   p += (size_t)NN * 4;
  int* off  = (int*)p;                   p += (size_t)(NN + 4) * 4;
  int* cur  = (int*)p;                   p += (size_t)NN * 4;
  int* sdst = (int*)p;                   p += (size_t)NE * 4;          // 2 MB
  float* sw = (float*)p;                 p += (size_t)NE * 4;          // 2 MB

  gemm_xw1_zero<<<320, 256, 0, stream>>>(x, W1, H0, cnt);
  hist_src<<<NE / 256, 256, 0, stream>>>(esrc, cnt);
  scan_offsets<<<1, 256, 0, stream>>>(cnt, off, cur);
  scatter_edges<<<NE / 256, 256, 0, stream>>>(esrc, edst, ew, cur, sdst, sw);
  spmm_g<<<NN / 4, 256, 0, stream>>>(off, sdst, sw, H0, W2, W3, G);
  spmm_zt<<<NN / 4, 256, 0, stream>>>(off, sdst, sw, G, R, M,
                                      zmean_out, zlog_out, ztb);

  dim3 g(NN / 1024, NN / 16, 1);
  adj_mfma<<<g, 256, 0, stream>>>(ztb, adj_out);
}